// Round 13
// baseline (1303.937 us; speedup 1.0000x reference)
//
#include <hip/hip_runtime.h>

#define T_STEPS 250
#define BATCH   256
#define IN_DIM  700
#define HID     1024
#define W_LD    1724   // = IN_DIM + HID
#define OUT_DIM 20
#define KP      704    // K padded to 22*32
#define KP4     (KP / 4)
#define NKT     (KP / 32)
#define CHUNK_T 50     // CUR chunk: 52 MB -> cache-resident (r8: FETCH 137->35MB)

typedef __attribute__((ext_vector_type(8))) short     bf16x8;
typedef __attribute__((ext_vector_type(8))) unsigned short u16x8;
typedef __attribute__((ext_vector_type(4))) float     f32x4;
typedef unsigned long long u64;

__device__ inline unsigned short f2bf(float f) {
    unsigned int u = __float_as_uint(f);
    unsigned int r = u + 0x7FFFu + ((u >> 16) & 1u);
    return (unsigned short)(r >> 16);
}

// ---------------------------------------------------------------------------
// WhhT_bf16[j][h] = bf16(W_h[h][700 + j]);  row 1024 is a zero sentinel row.
// ---------------------------------------------------------------------------
__global__ __launch_bounds__(256)
void trans_whh_bf16(const float* __restrict__ W_h, unsigned short* __restrict__ WhhT) {
    __shared__ float tile[32][33];
    const int bx = blockIdx.x * 32;  // h base
    const int by = blockIdx.y * 32;  // j base
    const int tx = threadIdx.x, ty = threadIdx.y;
#pragma unroll
    for (int i = 0; i < 32; i += 8)
        tile[ty + i][tx] = W_h[(size_t)(bx + ty + i) * W_LD + IN_DIM + by + tx];
    __syncthreads();
#pragma unroll
    for (int i = 0; i < 32; i += 8)
        WhhT[(size_t)(by + ty + i) * HID + bx + tx] = f2bf(tile[tx][ty + i]);
}

// WoT[h][o] = Wo[o][h]
__global__ __launch_bounds__(256)
void trans_wo(const float* __restrict__ Wo, float* __restrict__ WoT) {
    const int h = blockIdx.x * 256 + threadIdx.x;
    if (h >= HID) return;
#pragma unroll
    for (int o = 0; o < OUT_DIM; ++o)
        WoT[(size_t)h * OUT_DIM + o] = Wo[(size_t)o * HID + h];
}

// ---------------------------------------------------------------------------
// Pack x rows -> zero-padded K=704 bf16
// ---------------------------------------------------------------------------
__global__ __launch_bounds__(256)
void pack_x_bf16(const float* __restrict__ x, unsigned short* __restrict__ Xp, int rows) {
    const int total = rows * KP4;
    for (int idx = blockIdx.x * blockDim.x + threadIdx.x; idx < total;
         idx += gridDim.x * blockDim.x) {
        const int r = idx / KP4;
        const int c = idx - r * KP4;
        ushort4 o = make_ushort4(0, 0, 0, 0);
        if (c < IN_DIM / 4) {
            float4 v = *(const float4*)(x + (size_t)r * IN_DIM + c * 4);
            o = make_ushort4(f2bf(v.x), f2bf(v.y), f2bf(v.z), f2bf(v.w));
        }
        ((ushort4*)Xp)[(size_t)r * KP4 + c] = o;
    }
}

// Pack W_h's first 700 cols (ld 1724) -> [1024][704] bf16
__global__ __launch_bounds__(256)
void pack_w_bf16(const float* __restrict__ W_h, unsigned short* __restrict__ Wp) {
    const int total = HID * KP4;
    for (int idx = blockIdx.x * blockDim.x + threadIdx.x; idx < total;
         idx += gridDim.x * blockDim.x) {
        const int r = idx / KP4;
        const int c = idx - r * KP4;
        ushort4 o = make_ushort4(0, 0, 0, 0);
        if (c < IN_DIM / 4) {
            float4 v = *(const float4*)(W_h + (size_t)r * W_LD + c * 4);
            o = make_ushort4(f2bf(v.x), f2bf(v.y), f2bf(v.z), f2bf(v.w));
        }
        ((ushort4*)Wp)[(size_t)r * KP4 + c] = o;
    }
}

// ---------------------------------------------------------------------------
// bf16 MFMA GEMM: 128x128 tile, BK=32, 4 waves. (unchanged)
// ---------------------------------------------------------------------------
__global__ __launch_bounds__(256)
void mfma_gemm(const unsigned short* __restrict__ A,
               const unsigned short* __restrict__ B, float* __restrict__ C) {
    __shared__ unsigned short lA[128 * 32];
    __shared__ unsigned short lB[128 * 32];
    const int tid  = threadIdx.x;
    const int wid  = tid >> 6, lane = tid & 63;
    const int wr   = wid >> 1, wc = wid & 1;
    const size_t bm = (size_t)blockIdx.x * 128;
    const size_t bn = (size_t)blockIdx.y * 128;

    const int srow = tid >> 2;
    const int skq  = (tid & 3) * 8;

    const int wb0 = (srow * 64 + (tid & 3) * 16) ^ ((srow & 7) << 4);
    const int wb1 = ((srow + 64) * 64 + (tid & 3) * 16) ^ ((srow & 7) << 4);

    const unsigned short* pa = A + (bm + srow) * KP + skq;
    const unsigned short* pb = B + (bn + srow) * KP + skq;

    u16x8 ra0, ra1, rb0, rb1;
    auto ldg = [&](int k0) {
        ra0 = *(const u16x8*)(pa + k0);
        ra1 = *(const u16x8*)(pa + (size_t)64 * KP + k0);
        rb0 = *(const u16x8*)(pb + k0);
        rb1 = *(const u16x8*)(pb + (size_t)64 * KP + k0);
    };

    const int arow = wr * 64 + (lane & 15);
    const int brow = wc * 64 + (lane & 15);
    const int fq   = (lane >> 4) * 16;

    f32x4 acc[4][4];
#pragma unroll
    for (int m = 0; m < 4; ++m)
#pragma unroll
        for (int n = 0; n < 4; ++n) acc[m][n] = (f32x4){0.f, 0.f, 0.f, 0.f};

    ldg(0);
    for (int kt = 0; kt < NKT; ++kt) {
        *(u16x8*)((char*)lA + wb0) = ra0;
        *(u16x8*)((char*)lA + wb1) = ra1;
        *(u16x8*)((char*)lB + wb0) = rb0;
        *(u16x8*)((char*)lB + wb1) = rb1;
        __syncthreads();
        if (kt + 1 < NKT) ldg((kt + 1) * 32);
        bf16x8 af[4], bf[4];
#pragma unroll
        for (int m = 0; m < 4; ++m) {
            const int row = arow + m * 16;
            af[m] = *(const bf16x8*)((const char*)lA + ((row * 64 + fq) ^ ((row & 7) << 4)));
        }
#pragma unroll
        for (int n = 0; n < 4; ++n) {
            const int row = brow + n * 16;
            bf[n] = *(const bf16x8*)((const char*)lB + ((row * 64 + fq) ^ ((row & 7) << 4)));
        }
#pragma unroll
        for (int m = 0; m < 4; ++m)
#pragma unroll
            for (int n = 0; n < 4; ++n)
                acc[m][n] = __builtin_amdgcn_mfma_f32_16x16x32_bf16(af[m], bf[n], acc[m][n], 0, 0, 0);
        __syncthreads();
    }
#pragma unroll
    for (int m = 0; m < 4; ++m)
#pragma unroll
        for (int r = 0; r < 4; ++r) {
            float* cp = C + (bm + wr * 64 + m * 16 + (lane >> 4) * 4 + r) * HID
                          + bn + wc * 64 + (lane & 15);
#pragma unroll
            for (int n = 0; n < 4; ++n) cp[n * 16] = acc[m][n][r];
        }
}

// ---------------------------------------------------------------------------
// Persistent ALIF scan v10: 1 block = 1 batch, 4 waves split by DESTINATION
// neuron (wave wv owns neurons [wv*256, wv*256+256), 4/lane). Each wave
// gathers ALL spikes but only its 256-col slice (uint2 8B, fully coalesced).
// NO rec exchange (rec complete per wave); update once per neuron; spike
// lists published per wave via tiny LDS segments; 1 barrier/step.
// ---------------------------------------------------------------------------
#define XPULL(jd) {                                                          \
    if (!mm) { mm = mx1; kb = 1; mx1 = 0; }                                  \
    if (!mm) { mm = mx2; kb = 2; mx2 = 0; }                                  \
    if (!mm) { mm = mx3; kb = 3; mx3 = 0; }                                  \
    if (mm) { const int l_ = (int)__ffsll(mm) - 1; mm &= mm - 1;             \
              jd = jbase + l_ * 4 + kb; }                                    \
    else jd = 1024; }

#define GISS(a0_,a1_,a2_,a3_,a4_,a5_,a6_,a7_, iv_) {                         \
    a0_ = *(const uint2*)(Wbase + ((size_t)(unsigned short)iv_[0] << 10));   \
    a1_ = *(const uint2*)(Wbase + ((size_t)(unsigned short)iv_[1] << 10));   \
    a2_ = *(const uint2*)(Wbase + ((size_t)(unsigned short)iv_[2] << 10));   \
    a3_ = *(const uint2*)(Wbase + ((size_t)(unsigned short)iv_[3] << 10));   \
    a4_ = *(const uint2*)(Wbase + ((size_t)(unsigned short)iv_[4] << 10));   \
    a5_ = *(const uint2*)(Wbase + ((size_t)(unsigned short)iv_[5] << 10));   \
    a6_ = *(const uint2*)(Wbase + ((size_t)(unsigned short)iv_[6] << 10));   \
    a7_ = *(const uint2*)(Wbase + ((size_t)(unsigned short)iv_[7] << 10)); }

#define GACC1(w_) {                                                          \
    rec[0] += __uint_as_float(w_.x << 16);                                   \
    rec[1] += __uint_as_float(w_.x & 0xFFFF0000u);                           \
    rec[2] += __uint_as_float(w_.y << 16);                                   \
    rec[3] += __uint_as_float(w_.y & 0xFFFF0000u); }

#define GACC8(a0_,a1_,a2_,a3_,a4_,a5_,a6_,a7_) {                             \
    GACC1(a0_); GACC1(a1_); GACC1(a2_); GACC1(a3_);                          \
    GACC1(a4_); GACC1(a5_); GACC1(a6_); GACC1(a7_); }

// build this wave's spike list segment from its 4 ballots into buffer pbn
#define BUILD_LIST(pbn, c0_) {                                               \
    int cnt_ = c0_ > 64 ? 64 : c0_;                                          \
    unsigned short* L = &s_list[pbn][wv][0];                                 \
    const int jbase = wv * 256;                                              \
    u64 mm = bb0, mx1 = bb1, mx2 = bb2, mx3 = bb3; int kb = 0;               \
    { int ta,tb,tc2,td,te,tf,tg,th;                                          \
      XPULL(ta); XPULL(tb); XPULL(tc2); XPULL(td);                           \
      XPULL(te); XPULL(tf); XPULL(tg); XPULL(th);                            \
      L[0]=(unsigned short)ta; L[1]=(unsigned short)tb;                      \
      L[2]=(unsigned short)tc2; L[3]=(unsigned short)td;                     \
      L[4]=(unsigned short)te; L[5]=(unsigned short)tf;                      \
      L[6]=(unsigned short)tg; L[7]=(unsigned short)th; }                    \
    if (cnt_ > 8) {                                                          \
      int ta,tb,tc2,td,te,tf,tg,th;                                          \
      XPULL(ta); XPULL(tb); XPULL(tc2); XPULL(td);                           \
      XPULL(te); XPULL(tf); XPULL(tg); XPULL(th);                            \
      L[8]=(unsigned short)ta; L[9]=(unsigned short)tb;                      \
      L[10]=(unsigned short)tc2; L[11]=(unsigned short)td;                   \
      L[12]=(unsigned short)te; L[13]=(unsigned short)tf;                    \
      L[14]=(unsigned short)tg; L[15]=(unsigned short)th; }                  \
    if (cnt_ > 16) {                                                         \
      int ta,tb,tc2,td,te,tf,tg,th;                                          \
      XPULL(ta); XPULL(tb); XPULL(tc2); XPULL(td);                           \
      XPULL(te); XPULL(tf); XPULL(tg); XPULL(th);                            \
      L[16]=(unsigned short)ta; L[17]=(unsigned short)tb;                    \
      L[18]=(unsigned short)tc2; L[19]=(unsigned short)td;                   \
      L[20]=(unsigned short)te; L[21]=(unsigned short)tf;                    \
      L[22]=(unsigned short)tg; L[23]=(unsigned short)th; }                  \
    if (cnt_ > 24) {                                                         \
      int idx = 24;                                                          \
      while (idx < cnt_) { int jt; XPULL(jt); L[idx++] = (unsigned short)jt; } \
      while (idx & 7)    { L[idx++] = 1024; }                                \
    }                                                                        \
    s_cnt[pbn][wv] = cnt_; }

__global__ __launch_bounds__(256, 1)
void alif_scan(const float* __restrict__ CUR, const unsigned short* __restrict__ WhhT,
               const float* __restrict__ tau_mem, const float* __restrict__ tau_adp,
               float* __restrict__ zS, float* __restrict__ uS, float* __restrict__ aS,
               float* __restrict__ spkS, u64* __restrict__ masksW,
               int t0, int tc) {
    const int tid  = threadIdx.x;
    const int wv   = tid >> 6;         // wave 0..3, owns neurons [wv*256, wv*256+256)
    const int lane = tid & 63;
    const int b    = blockIdx.x;
    const int h0   = wv * 256 + lane * 4;   // this thread's 4 neurons

    __shared__ __align__(16) unsigned short s_list[2][4][64];  // [buf][seg][slot]
    __shared__ int s_cnt[2][4];
    __shared__ int s_spk;

    float u[4], a[4], alpha[4], rho[4];
    {
        f32x4 uu = *(const f32x4*)(uS + (size_t)b * HID + h0);
        f32x4 aa = *(const f32x4*)(aS + (size_t)b * HID + h0);
        f32x4 tm = *(const f32x4*)(tau_mem + h0);
        f32x4 ta = *(const f32x4*)(tau_adp + h0);
#pragma unroll
        for (int k = 0; k < 4; ++k) {
            u[k] = uu[k];  a[k] = aa[k];
            alpha[k] = expf(-1.f / tm[k]);
            rho[k]   = expf(-1.f / ta[k]);
        }
    }
    unsigned int zb = 0;   // 4 bits: this thread's neurons
    {
        f32x4 zz = *(const f32x4*)(zS + (size_t)b * HID + h0);
#pragma unroll
        for (int k = 0; k < 4; ++k)
            if (zz[k] > 0.5f) zb |= (1u << k);
    }
    if (tid == 0) s_spk = 0;

    // initial ballots + list build into buffer 0
    {
        u64 bb0 = __ballot((zb & 1u) != 0u);
        u64 bb1 = __ballot((zb & 2u) != 0u);
        u64 bb2 = __ballot((zb & 4u) != 0u);
        u64 bb3 = __ballot((zb & 8u) != 0u);
        const int cc = __popcll(bb0) + __popcll(bb1) + __popcll(bb2) + __popcll(bb3);
        BUILD_LIST(0, cc);
    }

    const unsigned short* Wbase = WhhT + h0;
    float xc[4];
    {
        f32x4 v = *(const f32x4*)(CUR + (size_t)b * HID + h0);
        xc[0]=v[0]; xc[1]=v[1]; xc[2]=v[2]; xc[3]=v[3];
    }
    __syncthreads();

    int wspk = 0;
    for (int tt = 0; tt < tc; ++tt) {
        const int pb = tt & 1;

        // prefetch next step's input current (L2-resident chunk)
        float xn[4];
        {
            const int tn = (tt + 1 < tc) ? tt + 1 : tt;
            f32x4 v = *(const f32x4*)(CUR + ((size_t)tn * BATCH + b) * HID + h0);
            xn[0]=v[0]; xn[1]=v[1]; xn[2]=v[2]; xn[3]=v[3];
        }

        float rec[4];
        rec[0] = 0.f; rec[1] = 0.f; rec[2] = 0.f; rec[3] = 0.f;

        // ---- gather all spikes' 8B slices, A/B pipelined over 8-groups ----
        {
            uint2 A0,A1,A2,A3,A4,A5,A6,A7;
            uint2 B0,B1,B2,B3,B4,B5,B6,B7;
            int pend = 0;
#pragma unroll 1
            for (int seg = 0; seg < 4; ++seg) {
                const int c  = s_cnt[pb][seg];
                const int ng = (c + 7) >> 3;
                const unsigned short* Lr = &s_list[pb][seg][0];
#pragma unroll 1
                for (int g = 0; g < ng; ++g) {
                    const u16x8 iv = *(const u16x8*)(Lr + g * 8);
                    if (pend == 1) {
                        GISS(B0,B1,B2,B3,B4,B5,B6,B7, iv);
                        GACC8(A0,A1,A2,A3,A4,A5,A6,A7);
                        pend = 2;
                    } else if (pend == 2) {
                        GISS(A0,A1,A2,A3,A4,A5,A6,A7, iv);
                        GACC8(B0,B1,B2,B3,B4,B5,B6,B7);
                        pend = 1;
                    } else {
                        GISS(A0,A1,A2,A3,A4,A5,A6,A7, iv);
                        pend = 1;
                    }
                }
            }
            if (pend == 1)      { GACC8(A0,A1,A2,A3,A4,A5,A6,A7); }
            else if (pend == 2) { GACC8(B0,B1,B2,B3,B4,B5,B6,B7); }
        }

        // ---- neuron update (4 neurons, once — not replicated) ----
        unsigned int znb = 0;
#pragma unroll
        for (int k = 0; k < 4; ++k) {
            const float z   = (zb >> k) & 1 ? 1.f : 0.f;
            const float omr = 1.f - rho[k];
            const float oma = 1.f - alpha[k];
            a[k] = rho[k] * a[k] + omr * z;
            const float th = 0.01f + 1.8f * a[k];
            u[k] = alpha[k] * u[k] + oma * (xc[k] + rec[k]) - z * th;
            if (u[k] - th > 0.f) znb |= (1u << k);
        }
        zb = znb;

        // ---- ballots, mask store, next-step list build ----
        {
            u64 bb0 = __ballot((zb & 1u) != 0u);
            u64 bb1 = __ballot((zb & 2u) != 0u);
            u64 bb2 = __ballot((zb & 4u) != 0u);
            u64 bb3 = __ballot((zb & 8u) != 0u);
            const int cc = __popcll(bb0) + __popcll(bb1) + __popcll(bb2) + __popcll(bb3);
            wspk += cc;
            if (lane < 4) {
                u64 v = lane == 0 ? bb0 : lane == 1 ? bb1 : lane == 2 ? bb2 : bb3;
                masksW[((size_t)(t0 + tt) * BATCH + b) * 16 + wv * 4 + lane] = v;
            }
            BUILD_LIST(pb ^ 1, cc);
        }

        xc[0]=xn[0]; xc[1]=xn[1]; xc[2]=xn[2]; xc[3]=xn[3];
        __syncthreads();   // publish lists for step tt+1
    }

    // write back state (each wave owns its neuron quarter)
    {
        f32x4 zo, uo, ao;
#pragma unroll
        for (int k = 0; k < 4; ++k) {
            zo[k] = (zb >> k) & 1 ? 1.f : 0.f;
            uo[k] = u[k];  ao[k] = a[k];
        }
        *(f32x4*)(zS + (size_t)b * HID + h0) = zo;
        *(f32x4*)(uS + (size_t)b * HID + h0) = uo;
        *(f32x4*)(aS + (size_t)b * HID + h0) = ao;
    }
    if (lane == 0) atomicAdd(&s_spk, wspk);
    __syncthreads();
    if (tid == 0 && s_spk) atomicAdd(spkS, (float)s_spk);
}

// ---------------------------------------------------------------------------
// y[t*B+b][o] = sum over spiking j of WoT[j][o]  (one wave per (t,b) pair)
// mask word w (0..15): wv2 = w>>2, k = w&3; bit l -> j = wv2*256 + l*4 + k
// ---------------------------------------------------------------------------
__global__ __launch_bounds__(256)
void readout_y(const u64* __restrict__ masks, const float* __restrict__ WoT,
               float* __restrict__ y, int npairs) {
    const int pr   = blockIdx.x * 4 + (threadIdx.x >> 6);
    const int lane = threadIdx.x & 63;
    if (pr >= npairs) return;
    const u64* mp = masks + (size_t)pr * 16;
    float acc = 0.f;
#pragma unroll 4
    for (int w = 0; w < 16; ++w) {
        u64 m = mp[w];
        const int jb = (w >> 2) * 256 + (w & 3);
        while (m) {
            const int l = __ffsll((unsigned long long)m) - 1;
            m &= m - 1;
            if (lane < OUT_DIM) acc += WoT[(size_t)(jb + l * 4) * OUT_DIM + lane];
        }
    }
    if (lane < OUT_DIM) y[(size_t)pr * OUT_DIM + lane] = acc;
}

// ---------------------------------------------------------------------------
// outputs[t][b][o] = EWA over t of y; writes final ouT.
// ---------------------------------------------------------------------------
__global__ __launch_bounds__(256)
void ewa_out(const float* __restrict__ y, const float* __restrict__ tau_out,
             float* __restrict__ outputs, float* __restrict__ ouS) {
    const int idx = blockIdx.x * 256 + threadIdx.x;
    if (idx >= BATCH * OUT_DIM) return;
    const int o = idx % OUT_DIM;
    const float ao = expf(-1.f / tau_out[o]);
    float ou = ouS[idx];
    for (int t = 0; t < T_STEPS; ++t) {
        const float v = y[(size_t)t * BATCH * OUT_DIM + idx];
        ou = ao * ou + (1.f - ao) * v;
        outputs[(size_t)t * BATCH * OUT_DIM + idx] = ou;
    }
    ouS[idx] = ou;
}

// ---------------------------------------------------------------------------
extern "C" void kernel_launch(void* const* d_in, const int* in_sizes, int n_in,
                              void* d_out, int out_size, void* d_ws, size_t ws_size,
                              hipStream_t stream) {
    (void)in_sizes; (void)n_in; (void)out_size;
    const float* x       = (const float*)d_in[0];
    const float* W_h     = (const float*)d_in[1];
    const float* tau_mem = (const float*)d_in[2];
    const float* tau_adp = (const float*)d_in[3];
    const float* W_o     = (const float*)d_in[4];
    const float* tau_out = (const float*)d_in[5];

    float* out     = (float*)d_out;
    float* outputs = out;                                      // [250][256][20]
    float* zS  = out + (size_t)T_STEPS * BATCH * OUT_DIM;      // [256][1024]
    float* uS  = zS + (size_t)BATCH * HID;
    float* aS  = uS + (size_t)BATCH * HID;
    float* ouS = aS + (size_t)BATCH * HID;                     // [256][20]
    float* spk = ouS + (size_t)BATCH * OUT_DIM;                // scalar

    // ws layout (bytes)
    char* w = (char*)d_ws;
    unsigned short* WhhT = (unsigned short*)w; w += (size_t)(HID + 1) * HID * 2;  // 2 MB + zero row
    unsigned short* Wp   = (unsigned short*)w; w += (size_t)HID * KP * 2;         // 1.4 MB
    float*          WoT  = (float*)w;          w += (size_t)HID * OUT_DIM * 4;    // 80 KB
    u64*            masksW = (u64*)w;          w += (size_t)T_STEPS * BATCH * 16 * 8; // 8 MB
    float*          yBuf = (float*)w;          w += (size_t)T_STEPS * BATCH * OUT_DIM * 4; // 5 MB
    char*           dynb = w;

    const size_t fixed = (size_t)(dynb - (char*)d_ws);
    const size_t per_step = (size_t)BATCH * KP * 2 + (size_t)BATCH * HID * 4;
    const size_t avail = ws_size > fixed ? ws_size - fixed : 0;
    int CT = (int)(avail / per_step);
    if (CT > CHUNK_T) CT = CHUNK_T;
    if (CT < 1) CT = 1;

    hipMemsetAsync(zS, 0,
                   ((size_t)3 * BATCH * HID + BATCH * OUT_DIM + 1) * sizeof(float),
                   stream);
    hipMemsetAsync(WhhT + (size_t)HID * HID, 0, HID * sizeof(unsigned short), stream);
    trans_whh_bf16<<<dim3(32, 32), dim3(32, 8), 0, stream>>>(W_h, WhhT);
    pack_w_bf16<<<512, 256, 0, stream>>>(W_h, Wp);
    trans_wo<<<4, 256, 0, stream>>>(W_o, WoT);

    for (int t0 = 0; t0 < T_STEPS; t0 += CT) {
        const int tc = (T_STEPS - t0 < CT) ? (T_STEPS - t0) : CT;
        const int rows = tc * BATCH;
        unsigned short* Xp = (unsigned short*)dynb;
        float* CUR = (float*)(dynb + (size_t)rows * KP * 2);
        int pblocks = (rows * KP4 + 255) / 256;
        if (pblocks > 2048) pblocks = 2048;
        pack_x_bf16<<<pblocks, 256, 0, stream>>>(x + (size_t)t0 * BATCH * IN_DIM, Xp, rows);
        mfma_gemm<<<dim3(rows / 128, HID / 128), 256, 0, stream>>>(Xp, Wp, CUR);
        alif_scan<<<BATCH, 256, 0, stream>>>(CUR, WhhT, tau_mem, tau_adp,
                                             zS, uS, aS, spk, masksW, t0, tc);
    }

    const int npairs = T_STEPS * BATCH;
    readout_y<<<(npairs + 3) / 4, 256, 0, stream>>>(masksW, WoT, yBuf, npairs);
    ewa_out<<<(BATCH * OUT_DIM + 255) / 256, 256, 0, stream>>>(yBuf, tau_out, outputs, ouS);
}